// Round 1
// baseline (865.745 us; speedup 1.0000x reference)
//
#include <hip/hip_runtime.h>
#include <stdint.h>

#define N_BATCH 128
#define C_IN    156
#define T_SMP   156
#define H_HID   1024
#define O_OUT   20

// Baked permutation (from reference _top_down construction)
__constant__ int PERM_C[156] = {
  20,21,48,49,68,69,6,7,34,35,58,59,12,13,2,3,38,39,72,73,56,57,22,23,16,17,
  64,65,44,45,30,31,0,1,10,11,28,29,40,41,52,53,66,67,76,77,46,47,32,33,18,19,
  60,61,74,75,54,55,26,27,4,5,42,43,62,63,14,15,36,37,70,71,8,9,24,25,50,51,
  98,99,126,127,146,147,84,85,112,113,136,137,90,91,80,81,116,117,150,151,134,135,
  100,101,94,95,142,143,122,123,108,109,78,79,88,89,106,107,118,119,130,131,144,145,
  154,155,124,125,110,111,96,97,138,139,152,153,132,133,104,105,82,83,120,121,
  140,141,92,93,114,115,148,149,86,87,102,103,128,129
};

// ref_next[d] = REF_KERNEL[d+1] = -20*(d+1)*exp(-d), correctly-rounded fp32
__device__ __constant__ float REFN_C[15] = {
  -20.0f,
  -14.7151776468576930f,
  -8.1201169941967630f,
  -3.9829654694291155f,
  -1.8315638888734178f,
  -0.80855363989025606f,
  -0.34702530473329017f,
  -0.14590111448872258f,
  -0.060383273022452135f,
  -0.024681960817335913f,
  -0.0099879845477466679f,
  -0.0040084081896589585f,
  -0.0015974952118653345f,
  -0.00063348115597555236f,
  -0.00024945861573107036f
};

#define IIR_A  0.904837418035959573   // exp(-1/10)
#define IIR_CK 0.271828182845904524   // e/10

// ---------------------------------------------------------------------------
// K1: build packed active-index lists for both paths.
// main:  list_m[n][t]  = { c   : x[n,c,t]   != 0 }
// loc:   list_l[n][j]  = { tau : x[n,PERM[j],tau] != 0 }
// Packed 4 u8 indices per u32; padded with 156 (zero row in wT LDS).
// ---------------------------------------------------------------------------
__global__ void __launch_bounds__(256) k_build_lists(
    const float* __restrict__ x,
    uint32_t* __restrict__ lists_m, uint32_t* __restrict__ cnt_m,
    uint32_t* __restrict__ lists_l, uint32_t* __restrict__ cnt_l)
{
  extern __shared__ float xl[];            // [156*156]
  const int n = blockIdx.x;
  const float* xn = x + n * (C_IN * T_SMP);
  for (int i = threadIdx.x; i < C_IN * T_SMP; i += 256) xl[i] = xn[i];
  __syncthreads();
  const int t = threadIdx.x;
  if (t < T_SMP) {
    { // main path
      uint32_t* Lp = lists_m + (n * T_SMP + t) * 40;
      uint32_t w = 0; int cnt = 0, nw = 0;
      for (int c = 0; c < C_IN; ++c) {
        if (xl[c * T_SMP + t] > 0.5f) {
          w |= ((uint32_t)c) << ((cnt & 3) * 8);
          ++cnt;
          if ((cnt & 3) == 0) { Lp[nw++] = w; w = 0; }
        }
      }
      if (cnt & 3) {
        for (int k = cnt & 3; k < 4; ++k) w |= 156u << (k * 8);
        Lp[nw++] = w;
      }
      cnt_m[n * T_SMP + t] = (uint32_t)nw;
    }
    { // location path: step j = t, bits over tau at channel PERM[j]
      uint32_t* Lp = lists_l + (n * T_SMP + t) * 40;
      const int pc = PERM_C[t];
      uint32_t w = 0; int cnt = 0, nw = 0;
      for (int tau = 0; tau < T_SMP; ++tau) {
        if (xl[pc * T_SMP + tau] > 0.5f) {
          w |= ((uint32_t)tau) << ((cnt & 3) * 8);
          ++cnt;
          if ((cnt & 3) == 0) { Lp[nw++] = w; w = 0; }
        }
      }
      if (cnt & 3) {
        for (int k = cnt & 3; k < 4; ++k) w |= 156u << (k * 8);
        Lp[nw++] = w;
      }
      cnt_l[n * T_SMP + t] = (uint32_t)nw;
    }
  }
}

// ---------------------------------------------------------------------------
// K2: fused layer-1: dense (gather-sum, fp64) + psp (fp64 IIR) + spike scan.
// One thread per (n,h); weight chunk transposed in LDS [157][128] (row 156=0).
// Spikes emitted as 64-bit ballot words: s1m[(n*156+t)*16 + h/64].
// ---------------------------------------------------------------------------
__global__ void __launch_bounds__(128) k_layer1(
    const float* __restrict__ w_fc1, const float* __restrict__ w_loc1,
    const uint32_t* __restrict__ lists_m, const uint32_t* __restrict__ cnt_m,
    const uint32_t* __restrict__ lists_l, const uint32_t* __restrict__ cnt_l,
    uint64_t* __restrict__ s1m_m, uint64_t* __restrict__ s1m_l)
{
  extern __shared__ float wT[];            // [157][128]
  const int hc   = blockIdx.x;             // 0..7  (h chunk of 128)
  const int n    = blockIdx.y;
  const int path = blockIdx.z;
  const int tid  = threadIdx.x;
  const float* w = (path == 0) ? w_fc1 : w_loc1;
  const uint32_t* lists = (path == 0) ? lists_m : lists_l;
  const uint32_t* cnts  = (path == 0) ? cnt_m  : cnt_l;
  uint64_t* s1m = (path == 0) ? s1m_m : s1m_l;
  const int h0 = hc * 128;

  { // stage wT[c][tid] = w[(h0+tid)*156 + c]
    const float4* wr = (const float4*)(w + (size_t)(h0 + tid) * C_IN);
    #pragma unroll
    for (int c4 = 0; c4 < C_IN / 4; ++c4) {
      float4 v = wr[c4];
      wT[(c4 * 4 + 0) * 128 + tid] = v.x;
      wT[(c4 * 4 + 1) * 128 + tid] = v.y;
      wT[(c4 * 4 + 2) * 128 + tid] = v.z;
      wT[(c4 * 4 + 3) * 128 + tid] = v.w;
    }
    wT[156 * 128 + tid] = 0.0f;
  }
  __syncthreads();

  float pend[15];
  #pragma unroll
  for (int d = 0; d < 15; ++d) pend[d] = 0.0f;
  double e1 = 0.0, e2 = 0.0;
  const int lane = tid & 63;
  const int word = hc * 2 + (tid >> 6);

  for (int t = 0; t < T_SMP; ++t) {
    const int base = n * T_SMP + t;
    const int nw = (int)cnts[base];
    const uint32_t* Lp = lists + (size_t)base * 40;
    double a0 = 0.0, a1 = 0.0;
    for (int wi = 0; wi < nw; ++wi) {
      uint32_t pk = Lp[wi];
      int c0 = pk & 255, c1 = (pk >> 8) & 255, c2 = (pk >> 16) & 255, c3 = pk >> 24;
      float f0 = wT[c0 * 128 + tid];
      float f1 = wT[c1 * 128 + tid];
      float f2 = wT[c2 * 128 + tid];
      float f3 = wT[c3 * 128 + tid];
      a0 += (double)f0 + (double)f2;     // pair-sum of two floats is exact in double
      a1 += (double)f1 + (double)f3;
    }
    double upre = a0 + a1;
    e1 = IIR_A * e1 + upre;
    e2 = IIR_A * e2 + e1;
    float uf = (float)(IIR_CK * (e2 - e1));   // psp output, rounded to f32 (as ref)
    float um = uf + pend[0];
    float s  = (um >= 10.0f) ? 1.0f : 0.0f;
    #pragma unroll
    for (int d = 0; d < 14; ++d) pend[d] = fmaf(s, REFN_C[d], pend[d + 1]);
    pend[14] = s * REFN_C[14];
    uint64_t bal = __ballot(um >= 10.0f);
    if (lane == 0) s1m[(size_t)base * 16 + word] = bal;
  }
}

// ---------------------------------------------------------------------------
// K3: layer-2 dense via bitmask gather. One wave per (n,t); lanes 0..19 = o.
// w2T[h][o] in LDS. fp64 accumulate, store f32 u2pre[n][o][t].
// ---------------------------------------------------------------------------
__global__ void __launch_bounds__(256) k_layer2(
    const float* __restrict__ w_fc2, const float* __restrict__ w_loc2,
    const uint64_t* __restrict__ s1m_m, const uint64_t* __restrict__ s1m_l,
    float* __restrict__ u2_m, float* __restrict__ u2_l)
{
  extern __shared__ float w2T[];           // [1024][20]
  const int path = blockIdx.y;
  const float* w2 = (path == 0) ? w_fc2 : w_loc2;
  const uint64_t* s1m = (path == 0) ? s1m_m : s1m_l;
  float* u2 = (path == 0) ? u2_m : u2_l;
  for (int i = threadIdx.x; i < O_OUT * H_HID; i += 256) {
    int o = i / H_HID, h = i % H_HID;
    w2T[h * O_OUT + o] = w2[i];
  }
  __syncthreads();
  const int id   = blockIdx.x * 4 + (threadIdx.x >> 6);   // (n*156+t)
  const int lane = threadIdx.x & 63;
  const int n = id / T_SMP, t = id % T_SMP;
  const int o = (lane < O_OUT) ? lane : 0;                 // extra lanes broadcast-read
  double u = 0.0;
  const uint64_t* mp = s1m + (size_t)id * 16;
  for (int wi = 0; wi < 16; ++wi) {
    uint64_t m = mp[wi];
    while (m) {
      int b = __builtin_ctzll(m);
      m &= m - 1;
      u += (double)w2T[(wi * 64 + b) * O_OUT + o];
    }
  }
  if (lane < O_OUT) u2[((size_t)n * O_OUT + o) * T_SMP + t] = (float)u;
}

// ---------------------------------------------------------------------------
// K4: layer-2 psp (fp64 IIR) + spike scan, write concatenated output.
// One thread per (path, n, o) row.
// ---------------------------------------------------------------------------
__global__ void __launch_bounds__(256) k_psp_spike_out(
    const float* __restrict__ u2_m, const float* __restrict__ u2_l,
    float* __restrict__ out)
{
  const int rid = blockIdx.x * 256 + threadIdx.x;   // 0..5119
  const int p = rid / (N_BATCH * O_OUT);
  const int r = rid % (N_BATCH * O_OUT);            // n*20+o
  const float* base = ((p == 0) ? u2_m : u2_l) + (size_t)r * T_SMP;
  float* ob = out + (size_t)r * (2 * T_SMP) + p * T_SMP;
  float pend[15];
  #pragma unroll
  for (int d = 0; d < 15; ++d) pend[d] = 0.0f;
  double e1 = 0.0, e2 = 0.0;
  for (int t = 0; t < T_SMP; ++t) {
    double xv = (double)base[t];
    e1 = IIR_A * e1 + xv;
    e2 = IIR_A * e2 + e1;
    float uf = (float)(IIR_CK * (e2 - e1));
    float um = uf + pend[0];
    float s  = (um >= 10.0f) ? 1.0f : 0.0f;
    #pragma unroll
    for (int d = 0; d < 14; ++d) pend[d] = fmaf(s, REFN_C[d], pend[d + 1]);
    pend[14] = s * REFN_C[14];
    ob[t] = s;
  }
}

// ---------------------------------------------------------------------------
extern "C" void kernel_launch(void* const* d_in, const int* in_sizes, int n_in,
                              void* d_out, int out_size, void* d_ws, size_t ws_size,
                              hipStream_t stream) {
  const float* x      = (const float*)d_in[0];
  const float* w_fc1  = (const float*)d_in[1];
  const float* w_fc2  = (const float*)d_in[2];
  const float* w_loc1 = (const float*)d_in[3];
  const float* w_loc2 = (const float*)d_in[4];
  float* out = (float*)d_out;
  char* ws = (char*)d_ws;

  // workspace layout (256B aligned)
  uint32_t* lists_m = (uint32_t*)(ws + 0);          //  3,194,880
  uint32_t* lists_l = (uint32_t*)(ws + 3194880);    //  3,194,880
  uint32_t* cnt_m   = (uint32_t*)(ws + 6389760);    //     79,872
  uint32_t* cnt_l   = (uint32_t*)(ws + 6469632);    //     79,872
  uint64_t* s1m_m   = (uint64_t*)(ws + 6549504);    //  2,555,904
  uint64_t* s1m_l   = (uint64_t*)(ws + 9105408);    //  2,555,904
  float*    u2_m    = (float*)   (ws + 11661312);   //  1,597,440
  float*    u2_l    = (float*)   (ws + 13258752);   //  1,597,440  (end 14,856,192)

  hipLaunchKernelGGL(k_build_lists, dim3(128), dim3(256),
                     C_IN * T_SMP * sizeof(float), stream,
                     x, lists_m, cnt_m, lists_l, cnt_l);
  hipLaunchKernelGGL(k_layer1, dim3(8, 128, 2), dim3(128),
                     157 * 128 * sizeof(float), stream,
                     w_fc1, w_loc1, lists_m, cnt_m, lists_l, cnt_l, s1m_m, s1m_l);
  hipLaunchKernelGGL(k_layer2, dim3(4992, 2), dim3(256),
                     H_HID * O_OUT * sizeof(float), stream,
                     w_fc2, w_loc2, s1m_m, s1m_l, u2_m, u2_l);
  hipLaunchKernelGGL(k_psp_spike_out, dim3(20), dim3(256), 0, stream,
                     u2_m, u2_l, out);
}

// Round 2
// 411.916 us; speedup vs baseline: 2.1018x; 2.1018x over previous
//
#include <hip/hip_runtime.h>
#include <stdint.h>

#define N_BATCH 128
#define C_IN    156
#define T_SMP   156
#define H_HID   1024
#define O_OUT   20

// Baked permutation (from reference _top_down construction)
__constant__ int PERM_C[156] = {
  20,21,48,49,68,69,6,7,34,35,58,59,12,13,2,3,38,39,72,73,56,57,22,23,16,17,
  64,65,44,45,30,31,0,1,10,11,28,29,40,41,52,53,66,67,76,77,46,47,32,33,18,19,
  60,61,74,75,54,55,26,27,4,5,42,43,62,63,14,15,36,37,70,71,8,9,24,25,50,51,
  98,99,126,127,146,147,84,85,112,113,136,137,90,91,80,81,116,117,150,151,134,135,
  100,101,94,95,142,143,122,123,108,109,78,79,88,89,106,107,118,119,130,131,144,145,
  154,155,124,125,110,111,96,97,138,139,152,153,132,133,104,105,82,83,120,121,
  140,141,92,93,114,115,148,149,86,87,102,103,128,129
};

// ref_next[d] = REF_KERNEL[d+1] = -20*(d+1)*exp(-d), correctly-rounded fp32
__device__ __constant__ float REFN_C[15] = {
  -20.0f,
  -14.7151776468576930f,
  -8.1201169941967630f,
  -3.9829654694291155f,
  -1.8315638888734178f,
  -0.80855363989025606f,
  -0.34702530473329017f,
  -0.14590111448872258f,
  -0.060383273022452135f,
  -0.024681960817335913f,
  -0.0099879845477466679f,
  -0.0040084081896589585f,
  -0.0015974952118653345f,
  -0.00063348115597555236f,
  -0.00024945861573107036f
};

#define IIR_A  0.904837418035959573   // exp(-1/10)
#define IIR_CK 0.271828182845904524   // e/10

// ---------------------------------------------------------------------------
// K1: build packed active-index lists for both paths (unchanged, ~5us).
// ---------------------------------------------------------------------------
__global__ void __launch_bounds__(256) k_build_lists(
    const float* __restrict__ x,
    uint32_t* __restrict__ lists_m, uint32_t* __restrict__ cnt_m,
    uint32_t* __restrict__ lists_l, uint32_t* __restrict__ cnt_l)
{
  extern __shared__ float xl[];            // [156*156]
  const int n = blockIdx.x;
  const float* xn = x + n * (C_IN * T_SMP);
  for (int i = threadIdx.x; i < C_IN * T_SMP; i += 256) xl[i] = xn[i];
  __syncthreads();
  const int t = threadIdx.x;
  if (t < T_SMP) {
    { // main path
      uint32_t* Lp = lists_m + (n * T_SMP + t) * 40;
      uint32_t w = 0; int cnt = 0, nw = 0;
      for (int c = 0; c < C_IN; ++c) {
        if (xl[c * T_SMP + t] > 0.5f) {
          w |= ((uint32_t)c) << ((cnt & 3) * 8);
          ++cnt;
          if ((cnt & 3) == 0) { Lp[nw++] = w; w = 0; }
        }
      }
      if (cnt & 3) {
        for (int k = cnt & 3; k < 4; ++k) w |= 156u << (k * 8);
        Lp[nw++] = w;
      }
      cnt_m[n * T_SMP + t] = (uint32_t)nw;
    }
    { // location path
      uint32_t* Lp = lists_l + (n * T_SMP + t) * 40;
      const int pc = PERM_C[t];
      uint32_t w = 0; int cnt = 0, nw = 0;
      for (int tau = 0; tau < T_SMP; ++tau) {
        if (xl[pc * T_SMP + tau] > 0.5f) {
          w |= ((uint32_t)tau) << ((cnt & 3) * 8);
          ++cnt;
          if ((cnt & 3) == 0) { Lp[nw++] = w; w = 0; }
        }
      }
      if (cnt & 3) {
        for (int k = cnt & 3; k < 4; ++k) w |= 156u << (k * 8);
        Lp[nw++] = w;
      }
      cnt_l[n * T_SMP + t] = (uint32_t)nw;
    }
  }
}

// ---------------------------------------------------------------------------
// K2 v2: fused layer-1. 4 h per thread via ds_read_b128.
// Block: 256 thr = 4 waves = 4 batches sharing wT chunk of 256 h.
// LDS layout: wT[c*256 + lane*4 + j] = w[(h0 + j*64 + lane)*156 + c].
// Grid: (4 hc, 32 ngroup, 2 path) = 256 blocks, 1/CU (157KB LDS).
// ---------------------------------------------------------------------------
__global__ void __launch_bounds__(256, 1) k_layer1(
    const float* __restrict__ w_fc1, const float* __restrict__ w_loc1,
    const uint32_t* __restrict__ lists_m, const uint32_t* __restrict__ cnt_m,
    const uint32_t* __restrict__ lists_l, const uint32_t* __restrict__ cnt_l,
    uint64_t* __restrict__ s1m_m, uint64_t* __restrict__ s1m_l)
{
  extern __shared__ float wT[];            // [157][256]
  const int hc   = blockIdx.x;             // 0..3  (h chunk of 256)
  const int n0   = blockIdx.y * 4;
  const int path = blockIdx.z;
  const int tid  = threadIdx.x;
  const float* w = (path == 0) ? w_fc1 : w_loc1;
  const uint32_t* lists = (path == 0) ? lists_m : lists_l;
  const uint32_t* cnts  = (path == 0) ? cnt_m  : cnt_l;
  uint64_t* s1m = (path == 0) ? s1m_m : s1m_l;
  const int h0 = hc * 256;

  { // stage: thread tid owns h = h0 + (tid&3)*64 + (tid>>2), slot (tid>>2)*4+(tid&3)
    const int js = tid & 3, ls = tid >> 2;
    const int ht = h0 + js * 64 + ls;
    const int slot = ls * 4 + js;
    const float4* wr = (const float4*)(w + (size_t)ht * C_IN);
    #pragma unroll
    for (int c4 = 0; c4 < C_IN / 4; ++c4) {
      float4 v = wr[c4];
      wT[(c4 * 4 + 0) * 256 + slot] = v.x;
      wT[(c4 * 4 + 1) * 256 + slot] = v.y;
      wT[(c4 * 4 + 2) * 256 + slot] = v.z;
      wT[(c4 * 4 + 3) * 256 + slot] = v.w;
    }
    wT[156 * 256 + tid] = 0.0f;            // guard row (padded index 156)
  }
  __syncthreads();

  const int wv   = tid >> 6;               // wave -> batch offset
  const int lane = tid & 63;
  const int n    = n0 + wv;
  const int rbase = n * T_SMP;

  float pend[4][15];
  #pragma unroll
  for (int j = 0; j < 4; ++j)
    #pragma unroll
    for (int d = 0; d < 15; ++d) pend[j][d] = 0.0f;
  double e1[4] = {0,0,0,0}, e2[4] = {0,0,0,0};

  // prefetch t=0 list
  int nw = (int)cnts[rbase];
  uint4 pkA = *(const uint4*)(lists + (size_t)rbase * 40);
  uint4 pkB = *(const uint4*)(lists + (size_t)rbase * 40 + 4);

  for (int t = 0; t < T_SMP; ++t) {
    const int base = rbase + t;
    // issue next-t prefetch early (overlaps with compute below)
    const int basen = (t < T_SMP - 1) ? base + 1 : base;
    const int nw_n = (int)cnts[basen];
    const uint4 pkA_n = *(const uint4*)(lists + (size_t)basen * 40);
    const uint4 pkB_n = *(const uint4*)(lists + (size_t)basen * 40 + 4);

    double a0[4] = {0,0,0,0}, a1[4] = {0,0,0,0};

#define DOWORD(PK) do {                                                      \
    uint32_t pk_ = (PK);                                                     \
    int c0_ = pk_ & 255, c1_ = (pk_ >> 8) & 255,                             \
        c2_ = (pk_ >> 16) & 255, c3_ = pk_ >> 24;                            \
    float4 f0_ = *(const float4*)&wT[c0_ * 256 + lane * 4];                  \
    float4 f1_ = *(const float4*)&wT[c1_ * 256 + lane * 4];                  \
    float4 f2_ = *(const float4*)&wT[c2_ * 256 + lane * 4];                  \
    float4 f3_ = *(const float4*)&wT[c3_ * 256 + lane * 4];                  \
    a0[0] += (double)f0_.x + (double)f2_.x;                                  \
    a1[0] += (double)f1_.x + (double)f3_.x;                                  \
    a0[1] += (double)f0_.y + (double)f2_.y;                                  \
    a1[1] += (double)f1_.y + (double)f3_.y;                                  \
    a0[2] += (double)f0_.z + (double)f2_.z;                                  \
    a1[2] += (double)f1_.z + (double)f3_.z;                                  \
    a0[3] += (double)f0_.w + (double)f2_.w;                                  \
    a1[3] += (double)f1_.w + (double)f3_.w;                                  \
  } while (0)

    if (nw > 0) DOWORD(pkA.x);
    if (nw > 1) DOWORD(pkA.y);
    if (nw > 2) DOWORD(pkA.z);
    if (nw > 3) DOWORD(pkA.w);
    if (nw > 4) DOWORD(pkB.x);
    if (nw > 5) DOWORD(pkB.y);
    if (nw > 6) DOWORD(pkB.z);
    if (nw > 7) DOWORD(pkB.w);
    if (nw > 8) {   // rare tail (>32 active channels)
      const uint32_t* Lp = lists + (size_t)base * 40;
      for (int wi = 8; wi < nw; ++wi) DOWORD(Lp[wi]);
    }
#undef DOWORD

    uint64_t bal[4];
    #pragma unroll
    for (int j = 0; j < 4; ++j) {
      double upre = a0[j] + a1[j];
      e1[j] = IIR_A * e1[j] + upre;
      e2[j] = IIR_A * e2[j] + e1[j];
      float uf = (float)(IIR_CK * (e2[j] - e1[j]));
      float um = uf + pend[j][0];
      bool sp = (um >= 10.0f);
      float s = sp ? 1.0f : 0.0f;
      #pragma unroll
      for (int d = 0; d < 14; ++d) pend[j][d] = fmaf(s, REFN_C[d], pend[j][d + 1]);
      pend[j][14] = s * REFN_C[14];
      bal[j] = __ballot(sp);
    }
    if (lane == 0) {
      uint64_t* sp_ = s1m + (size_t)base * 16 + hc * 4;
      sp_[0] = bal[0]; sp_[1] = bal[1]; sp_[2] = bal[2]; sp_[3] = bal[3];
    }
    nw = nw_n; pkA = pkA_n; pkB = pkB_n;
  }
}

// ---------------------------------------------------------------------------
// K3 v2: layer-2 dense via bitmask, 64-lane parallel.
// Wave per (n,t): lane = (hw = lane>>2 word, og = lane&3 o-group).
// Each lane: walk set bits of its word, 5 LDS reads + 5 f64 adds per bit
// (o = og + 4m). Butterfly-reduce over hw axis. 512-thr blocks, 80KB LDS.
// ---------------------------------------------------------------------------
__global__ void __launch_bounds__(512, 1) k_layer2(
    const float* __restrict__ w_fc2, const float* __restrict__ w_loc2,
    const uint64_t* __restrict__ s1m_m, const uint64_t* __restrict__ s1m_l,
    float* __restrict__ u2_m, float* __restrict__ u2_l)
{
  extern __shared__ float w2T[];           // [1024][20]
  const int path = blockIdx.y;
  const float* w2 = (path == 0) ? w_fc2 : w_loc2;
  const uint64_t* s1m = (path == 0) ? s1m_m : s1m_l;
  float* u2 = (path == 0) ? u2_m : u2_l;
  for (int i = threadIdx.x; i < O_OUT * H_HID; i += 512) {
    int o = i / H_HID, h = i % H_HID;
    w2T[h * O_OUT + o] = w2[i];
  }
  __syncthreads();
  const int id   = blockIdx.x * 8 + (threadIdx.x >> 6);   // (n*156+t)
  const int lane = threadIdx.x & 63;
  const int n = id / T_SMP, t = id % T_SMP;
  const int hw = lane >> 2, og = lane & 3;

  uint64_t m = s1m[(size_t)id * 16 + hw];
  double acc0 = 0, acc1 = 0, acc2 = 0, acc3 = 0, acc4 = 0;
  while (m) {
    int b = __builtin_ctzll(m);
    m &= m - 1;
    const float* wp = &w2T[(hw * 64 + b) * O_OUT + og];
    acc0 += (double)wp[0];
    acc1 += (double)wp[4];
    acc2 += (double)wp[8];
    acc3 += (double)wp[12];
    acc4 += (double)wp[16];
  }
  #pragma unroll
  for (int off = 4; off <= 32; off <<= 1) {
    acc0 += __shfl_xor(acc0, off);
    acc1 += __shfl_xor(acc1, off);
    acc2 += __shfl_xor(acc2, off);
    acc3 += __shfl_xor(acc3, off);
    acc4 += __shfl_xor(acc4, off);
  }
  if (lane < 4) {
    u2[((size_t)n * O_OUT + og +  0) * T_SMP + t] = (float)acc0;
    u2[((size_t)n * O_OUT + og +  4) * T_SMP + t] = (float)acc1;
    u2[((size_t)n * O_OUT + og +  8) * T_SMP + t] = (float)acc2;
    u2[((size_t)n * O_OUT + og + 12) * T_SMP + t] = (float)acc3;
    u2[((size_t)n * O_OUT + og + 16) * T_SMP + t] = (float)acc4;
  }
}

// ---------------------------------------------------------------------------
// K4: layer-2 psp (fp64 IIR) + spike scan, write concatenated output.
// ---------------------------------------------------------------------------
__global__ void __launch_bounds__(256) k_psp_spike_out(
    const float* __restrict__ u2_m, const float* __restrict__ u2_l,
    float* __restrict__ out)
{
  const int rid = blockIdx.x * 256 + threadIdx.x;   // 0..5119
  const int p = rid / (N_BATCH * O_OUT);
  const int r = rid % (N_BATCH * O_OUT);            // n*20+o
  const float* base = ((p == 0) ? u2_m : u2_l) + (size_t)r * T_SMP;
  float* ob = out + (size_t)r * (2 * T_SMP) + p * T_SMP;
  float pend[15];
  #pragma unroll
  for (int d = 0; d < 15; ++d) pend[d] = 0.0f;
  double e1 = 0.0, e2 = 0.0;
  for (int t = 0; t < T_SMP; ++t) {
    double xv = (double)base[t];
    e1 = IIR_A * e1 + xv;
    e2 = IIR_A * e2 + e1;
    float uf = (float)(IIR_CK * (e2 - e1));
    float um = uf + pend[0];
    float s  = (um >= 10.0f) ? 1.0f : 0.0f;
    #pragma unroll
    for (int d = 0; d < 14; ++d) pend[d] = fmaf(s, REFN_C[d], pend[d + 1]);
    pend[14] = s * REFN_C[14];
    ob[t] = s;
  }
}

// ---------------------------------------------------------------------------
extern "C" void kernel_launch(void* const* d_in, const int* in_sizes, int n_in,
                              void* d_out, int out_size, void* d_ws, size_t ws_size,
                              hipStream_t stream) {
  const float* x      = (const float*)d_in[0];
  const float* w_fc1  = (const float*)d_in[1];
  const float* w_fc2  = (const float*)d_in[2];
  const float* w_loc1 = (const float*)d_in[3];
  const float* w_loc2 = (const float*)d_in[4];
  float* out = (float*)d_out;
  char* ws = (char*)d_ws;

  // workspace layout
  uint32_t* lists_m = (uint32_t*)(ws + 0);          //  3,194,880
  uint32_t* lists_l = (uint32_t*)(ws + 3194880);    //  3,194,880
  uint32_t* cnt_m   = (uint32_t*)(ws + 6389760);    //     79,872
  uint32_t* cnt_l   = (uint32_t*)(ws + 6469632);    //     79,872
  uint64_t* s1m_m   = (uint64_t*)(ws + 6549504);    //  2,555,904
  uint64_t* s1m_l   = (uint64_t*)(ws + 9105408);    //  2,555,904
  float*    u2_m    = (float*)   (ws + 11661312);   //  1,597,440
  float*    u2_l    = (float*)   (ws + 13258752);   //  1,597,440

  hipLaunchKernelGGL(k_build_lists, dim3(128), dim3(256),
                     C_IN * T_SMP * sizeof(float), stream,
                     x, lists_m, cnt_m, lists_l, cnt_l);
  hipLaunchKernelGGL(k_layer1, dim3(4, 32, 2), dim3(256),
                     157 * 256 * sizeof(float), stream,
                     w_fc1, w_loc1, lists_m, cnt_m, lists_l, cnt_l, s1m_m, s1m_l);
  hipLaunchKernelGGL(k_layer2, dim3(2496, 2), dim3(512),
                     H_HID * O_OUT * sizeof(float), stream,
                     w_fc2, w_loc2, s1m_m, s1m_l, u2_m, u2_l);
  hipLaunchKernelGGL(k_psp_spike_out, dim3(20), dim3(256), 0, stream,
                     u2_m, u2_l, out);
}

// Round 3
// 354.949 us; speedup vs baseline: 2.4391x; 1.1605x over previous
//
#include <hip/hip_runtime.h>
#include <stdint.h>

#define N_BATCH 128
#define C_IN    156
#define T_SMP   156
#define H_HID   1024
#define O_OUT   20

// Baked permutation (from reference _top_down construction)
__constant__ int PERM_C[156] = {
  20,21,48,49,68,69,6,7,34,35,58,59,12,13,2,3,38,39,72,73,56,57,22,23,16,17,
  64,65,44,45,30,31,0,1,10,11,28,29,40,41,52,53,66,67,76,77,46,47,32,33,18,19,
  60,61,74,75,54,55,26,27,4,5,42,43,62,63,14,15,36,37,70,71,8,9,24,25,50,51,
  98,99,126,127,146,147,84,85,112,113,136,137,90,91,80,81,116,117,150,151,134,135,
  100,101,94,95,142,143,122,123,108,109,78,79,88,89,106,107,118,119,130,131,144,145,
  154,155,124,125,110,111,96,97,138,139,152,153,132,133,104,105,82,83,120,121,
  140,141,92,93,114,115,148,149,86,87,102,103,128,129
};

// ref_next[d] = REF_KERNEL[d+1] = -20*(d+1)*exp(-d), correctly-rounded fp32
__device__ __constant__ float REFN_C[15] = {
  -20.0f,
  -14.7151776468576930f,
  -8.1201169941967630f,
  -3.9829654694291155f,
  -1.8315638888734178f,
  -0.80855363989025606f,
  -0.34702530473329017f,
  -0.14590111448872258f,
  -0.060383273022452135f,
  -0.024681960817335913f,
  -0.0099879845477466679f,
  -0.0040084081896589585f,
  -0.0015974952118653345f,
  -0.00063348115597555236f,
  -0.00024945861573107036f
};

#define IIR_A  0.904837418035959573   // exp(-1/10)
#define IIR_CK 0.271828182845904524   // e/10

// ---------------------------------------------------------------------------
// K1: build packed active-index lists for both paths.
// ---------------------------------------------------------------------------
__global__ void __launch_bounds__(256) k_build_lists(
    const float* __restrict__ x,
    uint32_t* __restrict__ lists_m, uint32_t* __restrict__ cnt_m,
    uint32_t* __restrict__ lists_l, uint32_t* __restrict__ cnt_l)
{
  extern __shared__ float xl[];            // [156*156]
  const int n = blockIdx.x;
  const float* xn = x + n * (C_IN * T_SMP);
  for (int i = threadIdx.x; i < C_IN * T_SMP; i += 256) xl[i] = xn[i];
  __syncthreads();
  const int t = threadIdx.x;
  if (t < T_SMP) {
    { // main path
      uint32_t* Lp = lists_m + (n * T_SMP + t) * 40;
      uint32_t w = 0; int cnt = 0, nw = 0;
      for (int c = 0; c < C_IN; ++c) {
        if (xl[c * T_SMP + t] > 0.5f) {
          w |= ((uint32_t)c) << ((cnt & 3) * 8);
          ++cnt;
          if ((cnt & 3) == 0) { Lp[nw++] = w; w = 0; }
        }
      }
      if (cnt & 3) {
        for (int k = cnt & 3; k < 4; ++k) w |= 156u << (k * 8);
        Lp[nw++] = w;
      }
      cnt_m[n * T_SMP + t] = (uint32_t)nw;
    }
    { // location path
      uint32_t* Lp = lists_l + (n * T_SMP + t) * 40;
      const int pc = PERM_C[t];
      uint32_t w = 0; int cnt = 0, nw = 0;
      for (int tau = 0; tau < T_SMP; ++tau) {
        if (xl[pc * T_SMP + tau] > 0.5f) {
          w |= ((uint32_t)tau) << ((cnt & 3) * 8);
          ++cnt;
          if ((cnt & 3) == 0) { Lp[nw++] = w; w = 0; }
        }
      }
      if (cnt & 3) {
        for (int k = cnt & 3; k < 4; ++k) w |= 156u << (k * 8);
        Lp[nw++] = w;
      }
      cnt_l[n * T_SMP + t] = (uint32_t)nw;
    }
  }
}

// ---------------------------------------------------------------------------
// K2 v3: fused layer-1. Chunk = 128 h (80KB LDS -> 2 blocks/CU, 8 waves/CU).
// Interleaved-pair layout: wT[c*128 + 2*lane + p] = w[h0 + p*64 + lane][c]
// -> ONE ds_read_b64 per (lane, active channel) fetches both h values
//    (contiguous 512B/wave = max 4-way bank conflict, vs 8-way b128 before).
// Block: 256 thr = 4 waves = 4 batches. Grid: (8 hc, 32 ng, 2 path).
// ---------------------------------------------------------------------------
__global__ void __launch_bounds__(256, 2) k_layer1(
    const float* __restrict__ w_fc1, const float* __restrict__ w_loc1,
    const uint32_t* __restrict__ lists_m, const uint32_t* __restrict__ cnt_m,
    const uint32_t* __restrict__ lists_l, const uint32_t* __restrict__ cnt_l,
    uint64_t* __restrict__ s1m_m, uint64_t* __restrict__ s1m_l)
{
  extern __shared__ float wT[];            // [157][128], interleaved pairs
  const int hc   = blockIdx.x;             // 0..7  (h chunk of 128)
  const int n0   = blockIdx.y * 4;
  const int path = blockIdx.z;
  const int tid  = threadIdx.x;
  const float* w = (path == 0) ? w_fc1 : w_loc1;
  const uint32_t* lists = (path == 0) ? lists_m : lists_l;
  const uint32_t* cnts  = (path == 0) ? cnt_m  : cnt_l;
  uint64_t* s1m = (path == 0) ? s1m_m : s1m_l;
  const int h0 = hc * 128;

  { // stage: thread tid owns h-row h' = tid&127, c-half = tid>>7
    const int hp   = tid & 127;
    const int c0   = (tid >> 7) * 78;
    const int slot = 2 * (hp & 63) + (hp >> 6);
    const float* wr = w + (size_t)(h0 + hp) * C_IN + c0;
    #pragma unroll
    for (int k = 0; k < 78; k += 2) {
      float2 v = *(const float2*)(wr + k);
      wT[(c0 + k) * 128 + slot]     = v.x;
      wT[(c0 + k + 1) * 128 + slot] = v.y;
    }
    if (tid < 128) wT[156 * 128 + tid] = 0.0f;   // guard row (padded index 156)
  }
  __syncthreads();

  const int wv   = tid >> 6;               // wave -> batch offset
  const int lane = tid & 63;
  const int n    = n0 + wv;
  const int rbase = n * T_SMP;
  const int lx2 = lane * 2;

  float pend[2][15];
  #pragma unroll
  for (int j = 0; j < 2; ++j)
    #pragma unroll
    for (int d = 0; d < 15; ++d) pend[j][d] = 0.0f;
  double e1[2] = {0,0}, e2[2] = {0,0};

  // prefetch t=0 list
  int nw = (int)cnts[rbase];
  uint4 pkA = *(const uint4*)(lists + (size_t)rbase * 40);
  uint4 pkB = *(const uint4*)(lists + (size_t)rbase * 40 + 4);

  for (int t = 0; t < T_SMP; ++t) {
    const int base = rbase + t;
    const int basen = (t < T_SMP - 1) ? base + 1 : base;
    const int nw_n = (int)cnts[basen];
    const uint4 pkA_n = *(const uint4*)(lists + (size_t)basen * 40);
    const uint4 pkB_n = *(const uint4*)(lists + (size_t)basen * 40 + 4);

    double a0[2] = {0,0}, a1[2] = {0,0};

#define DOWORD(PK) do {                                                      \
    uint32_t pk_ = (PK);                                                     \
    int c0_ = pk_ & 255, c1_ = (pk_ >> 8) & 255,                             \
        c2_ = (pk_ >> 16) & 255, c3_ = pk_ >> 24;                            \
    float2 F0 = *(const float2*)&wT[c0_ * 128 + lx2];                        \
    float2 F1 = *(const float2*)&wT[c1_ * 128 + lx2];                        \
    float2 F2 = *(const float2*)&wT[c2_ * 128 + lx2];                        \
    float2 F3 = *(const float2*)&wT[c3_ * 128 + lx2];                        \
    a0[0] += (double)F0.x + (double)F2.x;                                    \
    a1[0] += (double)F1.x + (double)F3.x;                                    \
    a0[1] += (double)F0.y + (double)F2.y;                                    \
    a1[1] += (double)F1.y + (double)F3.y;                                    \
  } while (0)

    if (nw > 0) DOWORD(pkA.x);
    if (nw > 1) DOWORD(pkA.y);
    if (nw > 2) DOWORD(pkA.z);
    if (nw > 3) DOWORD(pkA.w);
    if (nw > 4) DOWORD(pkB.x);
    if (nw > 5) DOWORD(pkB.y);
    if (nw > 6) DOWORD(pkB.z);
    if (nw > 7) DOWORD(pkB.w);
    if (nw > 8) {   // rare tail (>32 active channels)
      const uint32_t* Lp = lists + (size_t)base * 40;
      for (int wi = 8; wi < nw; ++wi) DOWORD(Lp[wi]);
    }
#undef DOWORD

    uint64_t bal[2];
    #pragma unroll
    for (int j = 0; j < 2; ++j) {
      double upre = a0[j] + a1[j];
      e1[j] = IIR_A * e1[j] + upre;
      e2[j] = IIR_A * e2[j] + e1[j];
      float uf = (float)(IIR_CK * (e2[j] - e1[j]));
      float um = uf + pend[j][0];
      bool sp = (um >= 10.0f);
      float s = sp ? 1.0f : 0.0f;
      #pragma unroll
      for (int d = 0; d < 14; ++d) pend[j][d] = fmaf(s, REFN_C[d], pend[j][d + 1]);
      pend[j][14] = s * REFN_C[14];
      bal[j] = __ballot(sp);
    }
    if (lane == 0) {
      uint64_t* sp_ = s1m + (size_t)base * 16 + hc * 2;
      sp_[0] = bal[0]; sp_[1] = bal[1];
    }
    nw = nw_n; pkA = pkA_n; pkB = pkB_n;
  }
}

// ---------------------------------------------------------------------------
// K3 v3: layer-2 dense via bitmask, 64-lane parallel, ONE block per (n,path).
// Stage w2T once (80KB), 8 waves each loop ~20 t values.
// Lane = (hw = lane>>2 word, og = lane&3 o-group); butterfly over hw axis.
// ---------------------------------------------------------------------------
__global__ void __launch_bounds__(512, 1) k_layer2(
    const float* __restrict__ w_fc2, const float* __restrict__ w_loc2,
    const uint64_t* __restrict__ s1m_m, const uint64_t* __restrict__ s1m_l,
    float* __restrict__ u2_m, float* __restrict__ u2_l)
{
  extern __shared__ float w2T[];           // [1024][20]
  const int path = blockIdx.y;
  const int n = blockIdx.x;
  const float* w2 = (path == 0) ? w_fc2 : w_loc2;
  const uint64_t* s1m = (path == 0) ? s1m_m : s1m_l;
  float* u2 = (path == 0) ? u2_m : u2_l;
  for (int i = threadIdx.x; i < O_OUT * H_HID; i += 512) {
    int o = i / H_HID, h = i % H_HID;
    w2T[h * O_OUT + o] = w2[i];
  }
  __syncthreads();
  const int wv   = threadIdx.x >> 6;
  const int lane = threadIdx.x & 63;
  const int hw = lane >> 2, og = lane & 3;

  for (int t = wv; t < T_SMP; t += 8) {
    const int id = n * T_SMP + t;
    uint64_t m = s1m[(size_t)id * 16 + hw];
    double acc0 = 0, acc1 = 0, acc2 = 0, acc3 = 0, acc4 = 0;
    while (m) {
      int b = __builtin_ctzll(m);
      m &= m - 1;
      const float* wp = &w2T[(hw * 64 + b) * O_OUT + og];
      acc0 += (double)wp[0];
      acc1 += (double)wp[4];
      acc2 += (double)wp[8];
      acc3 += (double)wp[12];
      acc4 += (double)wp[16];
    }
    #pragma unroll
    for (int off = 4; off <= 32; off <<= 1) {
      acc0 += __shfl_xor(acc0, off);
      acc1 += __shfl_xor(acc1, off);
      acc2 += __shfl_xor(acc2, off);
      acc3 += __shfl_xor(acc3, off);
      acc4 += __shfl_xor(acc4, off);
    }
    if (lane < 4) {
      u2[((size_t)n * O_OUT + og +  0) * T_SMP + t] = (float)acc0;
      u2[((size_t)n * O_OUT + og +  4) * T_SMP + t] = (float)acc1;
      u2[((size_t)n * O_OUT + og +  8) * T_SMP + t] = (float)acc2;
      u2[((size_t)n * O_OUT + og + 12) * T_SMP + t] = (float)acc3;
      u2[((size_t)n * O_OUT + og + 16) * T_SMP + t] = (float)acc4;
    }
  }
}

// ---------------------------------------------------------------------------
// K4: layer-2 psp (fp64 IIR) + spike scan, write concatenated output.
// ---------------------------------------------------------------------------
__global__ void __launch_bounds__(256) k_psp_spike_out(
    const float* __restrict__ u2_m, const float* __restrict__ u2_l,
    float* __restrict__ out)
{
  const int rid = blockIdx.x * 256 + threadIdx.x;   // 0..5119
  const int p = rid / (N_BATCH * O_OUT);
  const int r = rid % (N_BATCH * O_OUT);            // n*20+o
  const float* base = ((p == 0) ? u2_m : u2_l) + (size_t)r * T_SMP;
  float* ob = out + (size_t)r * (2 * T_SMP) + p * T_SMP;
  float pend[15];
  #pragma unroll
  for (int d = 0; d < 15; ++d) pend[d] = 0.0f;
  double e1 = 0.0, e2 = 0.0;
  for (int t = 0; t < T_SMP; ++t) {
    double xv = (double)base[t];
    e1 = IIR_A * e1 + xv;
    e2 = IIR_A * e2 + e1;
    float uf = (float)(IIR_CK * (e2 - e1));
    float um = uf + pend[0];
    float s  = (um >= 10.0f) ? 1.0f : 0.0f;
    #pragma unroll
    for (int d = 0; d < 14; ++d) pend[d] = fmaf(s, REFN_C[d], pend[d + 1]);
    pend[14] = s * REFN_C[14];
    ob[t] = s;
  }
}

// ---------------------------------------------------------------------------
extern "C" void kernel_launch(void* const* d_in, const int* in_sizes, int n_in,
                              void* d_out, int out_size, void* d_ws, size_t ws_size,
                              hipStream_t stream) {
  const float* x      = (const float*)d_in[0];
  const float* w_fc1  = (const float*)d_in[1];
  const float* w_fc2  = (const float*)d_in[2];
  const float* w_loc1 = (const float*)d_in[3];
  const float* w_loc2 = (const float*)d_in[4];
  float* out = (float*)d_out;
  char* ws = (char*)d_ws;

  // workspace layout
  uint32_t* lists_m = (uint32_t*)(ws + 0);          //  3,194,880
  uint32_t* lists_l = (uint32_t*)(ws + 3194880);    //  3,194,880
  uint32_t* cnt_m   = (uint32_t*)(ws + 6389760);    //     79,872
  uint32_t* cnt_l   = (uint32_t*)(ws + 6469632);    //     79,872
  uint64_t* s1m_m   = (uint64_t*)(ws + 6549504);    //  2,555,904
  uint64_t* s1m_l   = (uint64_t*)(ws + 9105408);    //  2,555,904
  float*    u2_m    = (float*)   (ws + 11661312);   //  1,597,440
  float*    u2_l    = (float*)   (ws + 13258752);   //  1,597,440

  hipLaunchKernelGGL(k_build_lists, dim3(128), dim3(256),
                     C_IN * T_SMP * sizeof(float), stream,
                     x, lists_m, cnt_m, lists_l, cnt_l);
  hipLaunchKernelGGL(k_layer1, dim3(8, 32, 2), dim3(256),
                     157 * 128 * sizeof(float), stream,
                     w_fc1, w_loc1, lists_m, cnt_m, lists_l, cnt_l, s1m_m, s1m_l);
  hipLaunchKernelGGL(k_layer2, dim3(128, 2), dim3(512),
                     H_HID * O_OUT * sizeof(float), stream,
                     w_fc2, w_loc2, s1m_m, s1m_l, u2_m, u2_l);
  hipLaunchKernelGGL(k_psp_spike_out, dim3(20), dim3(256), 0, stream,
                     u2_m, u2_l, out);
}

// Round 4
// 346.779 us; speedup vs baseline: 2.4965x; 1.0236x over previous
//
#include <hip/hip_runtime.h>
#include <stdint.h>

#define N_BATCH 128
#define C_IN    156
#define T_SMP   156
#define H_HID   1024
#define O_OUT   20

// Baked permutation (from reference _top_down construction)
__constant__ int PERM_C[156] = {
  20,21,48,49,68,69,6,7,34,35,58,59,12,13,2,3,38,39,72,73,56,57,22,23,16,17,
  64,65,44,45,30,31,0,1,10,11,28,29,40,41,52,53,66,67,76,77,46,47,32,33,18,19,
  60,61,74,75,54,55,26,27,4,5,42,43,62,63,14,15,36,37,70,71,8,9,24,25,50,51,
  98,99,126,127,146,147,84,85,112,113,136,137,90,91,80,81,116,117,150,151,134,135,
  100,101,94,95,142,143,122,123,108,109,78,79,88,89,106,107,118,119,130,131,144,145,
  154,155,124,125,110,111,96,97,138,139,152,153,132,133,104,105,82,83,120,121,
  140,141,92,93,114,115,148,149,86,87,102,103,128,129
};

// ref_next[d] = REF_KERNEL[d+1] = -20*(d+1)*exp(-d), correctly-rounded fp32
__device__ __constant__ float REFN_C[15] = {
  -20.0f,
  -14.7151776468576930f,
  -8.1201169941967630f,
  -3.9829654694291155f,
  -1.8315638888734178f,
  -0.80855363989025606f,
  -0.34702530473329017f,
  -0.14590111448872258f,
  -0.060383273022452135f,
  -0.024681960817335913f,
  -0.0099879845477466679f,
  -0.0040084081896589585f,
  -0.0015974952118653345f,
  -0.00063348115597555236f,
  -0.00024945861573107036f
};

#define IIR_A  0.904837418035959573   // exp(-1/10)
#define IIR_CK 0.271828182845904524   // e/10

// ---------------------------------------------------------------------------
// K1: build packed active-index lists for both paths.
// ---------------------------------------------------------------------------
__global__ void __launch_bounds__(256) k_build_lists(
    const float* __restrict__ x,
    uint32_t* __restrict__ lists_m, uint32_t* __restrict__ cnt_m,
    uint32_t* __restrict__ lists_l, uint32_t* __restrict__ cnt_l)
{
  extern __shared__ float xl[];            // [156*156]
  const int n = blockIdx.x;
  const float* xn = x + n * (C_IN * T_SMP);
  for (int i = threadIdx.x; i < C_IN * T_SMP; i += 256) xl[i] = xn[i];
  __syncthreads();
  const int t = threadIdx.x;
  if (t < T_SMP) {
    { // main path
      uint32_t* Lp = lists_m + (n * T_SMP + t) * 40;
      uint32_t w = 0; int cnt = 0, nw = 0;
      for (int c = 0; c < C_IN; ++c) {
        if (xl[c * T_SMP + t] > 0.5f) {
          w |= ((uint32_t)c) << ((cnt & 3) * 8);
          ++cnt;
          if ((cnt & 3) == 0) { Lp[nw++] = w; w = 0; }
        }
      }
      if (cnt & 3) {
        for (int k = cnt & 3; k < 4; ++k) w |= 156u << (k * 8);
        Lp[nw++] = w;
      }
      cnt_m[n * T_SMP + t] = (uint32_t)nw;
    }
    { // location path
      uint32_t* Lp = lists_l + (n * T_SMP + t) * 40;
      const int pc = PERM_C[t];
      uint32_t w = 0; int cnt = 0, nw = 0;
      for (int tau = 0; tau < T_SMP; ++tau) {
        if (xl[pc * T_SMP + tau] > 0.5f) {
          w |= ((uint32_t)tau) << ((cnt & 3) * 8);
          ++cnt;
          if ((cnt & 3) == 0) { Lp[nw++] = w; w = 0; }
        }
      }
      if (cnt & 3) {
        for (int k = cnt & 3; k < 4; ++k) w |= 156u << (k * 8);
        Lp[nw++] = w;
      }
      cnt_l[n * T_SMP + t] = (uint32_t)nw;
    }
  }
}

// ---------------------------------------------------------------------------
// K2 v4: fused layer-1. Chunk = 64 h, 1 h per lane.
// wT[c*64 + lane]: wave reads 64 consecutive floats -> conflict-free.
// LDS 40KB -> 4 blocks/CU = 16 waves/CU = 4 waves/SIMD.
// Wave-uniform list words go through readfirstlane -> index extraction on SALU.
// Block: 256 thr = 4 waves = 4 batches. Grid: (16 hc, 32 ng, 2 path).
// ---------------------------------------------------------------------------
__global__ void __launch_bounds__(256, 4) k_layer1(
    const float* __restrict__ w_fc1, const float* __restrict__ w_loc1,
    const uint32_t* __restrict__ lists_m, const uint32_t* __restrict__ cnt_m,
    const uint32_t* __restrict__ lists_l, const uint32_t* __restrict__ cnt_l,
    uint64_t* __restrict__ s1m_m, uint64_t* __restrict__ s1m_l)
{
  extern __shared__ float wT[];            // [157][64]
  const int hc   = blockIdx.x;             // 0..15 (h chunk of 64)
  const int n0   = blockIdx.y * 4;
  const int path = blockIdx.z;
  const int tid  = threadIdx.x;
  const float* w = (path == 0) ? w_fc1 : w_loc1;
  const uint32_t* lists = (path == 0) ? lists_m : lists_l;
  const uint32_t* cnts  = (path == 0) ? cnt_m  : cnt_l;
  uint64_t* s1m = (path == 0) ? s1m_m : s1m_l;
  const int h0 = hc * 64;

  { // stage: thread tid owns h-row hp = tid&63, c-quarter = tid>>6 (39 c each)
    const int hp = tid & 63;
    const int c0 = (tid >> 6) * 39;
    const float* wr = w + (size_t)(h0 + hp) * C_IN + c0;
    #pragma unroll
    for (int k = 0; k < 39; ++k) wT[(c0 + k) * 64 + hp] = wr[k];
    if (tid < 64) wT[156 * 64 + tid] = 0.0f;   // guard row (padded index 156)
  }
  __syncthreads();

  const int wv   = tid >> 6;               // wave -> batch offset
  const int lane = tid & 63;
  const int n    = n0 + wv;
  const int rbase = n * T_SMP;

  float pend[15];
  #pragma unroll
  for (int d = 0; d < 15; ++d) pend[d] = 0.0f;
  double e1 = 0.0, e2 = 0.0;

  // prefetch t=0 list
  int nw = (int)cnts[rbase];
  uint4 pkA = *(const uint4*)(lists + (size_t)rbase * 40);
  uint4 pkB = *(const uint4*)(lists + (size_t)rbase * 40 + 4);

  for (int t = 0; t < T_SMP; ++t) {
    const int base = rbase + t;
    const int basen = (t < T_SMP - 1) ? base + 1 : base;
    const int nw_n = (int)cnts[basen];
    const uint4 pkA_n = *(const uint4*)(lists + (size_t)basen * 40);
    const uint4 pkB_n = *(const uint4*)(lists + (size_t)basen * 40 + 4);

    double a0 = 0.0, a1 = 0.0;

#define DOWORD(PK) do {                                                      \
    uint32_t pk_ = __builtin_amdgcn_readfirstlane(PK);                       \
    int c0_ = pk_ & 255, c1_ = (pk_ >> 8) & 255,                             \
        c2_ = (pk_ >> 16) & 255, c3_ = pk_ >> 24;                            \
    float F0 = wT[c0_ * 64 + lane];                                          \
    float F1 = wT[c1_ * 64 + lane];                                          \
    float F2 = wT[c2_ * 64 + lane];                                          \
    float F3 = wT[c3_ * 64 + lane];                                          \
    a0 += (double)F0 + (double)F2;                                           \
    a1 += (double)F1 + (double)F3;                                           \
  } while (0)

    if (nw > 0) DOWORD(pkA.x);
    if (nw > 1) DOWORD(pkA.y);
    if (nw > 2) DOWORD(pkA.z);
    if (nw > 3) DOWORD(pkA.w);
    if (nw > 4) DOWORD(pkB.x);
    if (nw > 5) DOWORD(pkB.y);
    if (nw > 6) DOWORD(pkB.z);
    if (nw > 7) DOWORD(pkB.w);
    if (nw > 8) {   // rare tail (>32 active channels)
      const uint32_t* Lp = lists + (size_t)base * 40;
      for (int wi = 8; wi < nw; ++wi) DOWORD(Lp[wi]);
    }
#undef DOWORD

    double upre = a0 + a1;
    e1 = IIR_A * e1 + upre;
    e2 = IIR_A * e2 + e1;
    float uf = (float)(IIR_CK * (e2 - e1));
    float um = uf + pend[0];
    bool sp = (um >= 10.0f);
    float s = sp ? 1.0f : 0.0f;
    #pragma unroll
    for (int d = 0; d < 14; ++d) pend[d] = fmaf(s, REFN_C[d], pend[d + 1]);
    pend[14] = s * REFN_C[14];
    uint64_t bal = __ballot(sp);
    if (lane == 0) s1m[(size_t)base * 16 + hc] = bal;

    nw = nw_n; pkA = pkA_n; pkB = pkB_n;
  }
}

// ---------------------------------------------------------------------------
// K3 v4: layer-2 dense via bitmask, 64-lane parallel.
// Grid: (128 n x 4 t-chunks, 2 path); each block stages w2T (80KB) and
// covers 39 t with 8 waves (~5 t per wave).
// Lane = (hw = lane>>2 word, og = lane&3 o-group); butterfly over hw axis.
// ---------------------------------------------------------------------------
__global__ void __launch_bounds__(512, 1) k_layer2(
    const float* __restrict__ w_fc2, const float* __restrict__ w_loc2,
    const uint64_t* __restrict__ s1m_m, const uint64_t* __restrict__ s1m_l,
    float* __restrict__ u2_m, float* __restrict__ u2_l)
{
  extern __shared__ float w2T[];           // [1024][20]
  const int path = blockIdx.y;
  const int n  = blockIdx.x >> 2;
  const int tc = blockIdx.x & 3;
  const float* w2 = (path == 0) ? w_fc2 : w_loc2;
  const uint64_t* s1m = (path == 0) ? s1m_m : s1m_l;
  float* u2 = (path == 0) ? u2_m : u2_l;
  for (int i = threadIdx.x; i < O_OUT * H_HID; i += 512) {
    int o = i / H_HID, h = i % H_HID;
    w2T[h * O_OUT + o] = w2[i];
  }
  __syncthreads();
  const int wv   = threadIdx.x >> 6;
  const int lane = threadIdx.x & 63;
  const int hw = lane >> 2, og = lane & 3;

  for (int tt = wv; tt < 39; tt += 8) {
    const int t = tc * 39 + tt;
    const int id = n * T_SMP + t;
    uint64_t m = s1m[(size_t)id * 16 + hw];
    double acc0 = 0, acc1 = 0, acc2 = 0, acc3 = 0, acc4 = 0;
    while (m) {
      int b = __builtin_ctzll(m);
      m &= m - 1;
      const float* wp = &w2T[(hw * 64 + b) * O_OUT + og];
      acc0 += (double)wp[0];
      acc1 += (double)wp[4];
      acc2 += (double)wp[8];
      acc3 += (double)wp[12];
      acc4 += (double)wp[16];
    }
    #pragma unroll
    for (int off = 4; off <= 32; off <<= 1) {
      acc0 += __shfl_xor(acc0, off);
      acc1 += __shfl_xor(acc1, off);
      acc2 += __shfl_xor(acc2, off);
      acc3 += __shfl_xor(acc3, off);
      acc4 += __shfl_xor(acc4, off);
    }
    if (lane < 4) {
      u2[((size_t)n * O_OUT + og +  0) * T_SMP + t] = (float)acc0;
      u2[((size_t)n * O_OUT + og +  4) * T_SMP + t] = (float)acc1;
      u2[((size_t)n * O_OUT + og +  8) * T_SMP + t] = (float)acc2;
      u2[((size_t)n * O_OUT + og + 12) * T_SMP + t] = (float)acc3;
      u2[((size_t)n * O_OUT + og + 16) * T_SMP + t] = (float)acc4;
    }
  }
}

// ---------------------------------------------------------------------------
// K4: layer-2 psp (fp64 IIR) + spike scan, write concatenated output.
// ---------------------------------------------------------------------------
__global__ void __launch_bounds__(256) k_psp_spike_out(
    const float* __restrict__ u2_m, const float* __restrict__ u2_l,
    float* __restrict__ out)
{
  const int rid = blockIdx.x * 256 + threadIdx.x;   // 0..5119
  const int p = rid / (N_BATCH * O_OUT);
  const int r = rid % (N_BATCH * O_OUT);            // n*20+o
  const float* base = ((p == 0) ? u2_m : u2_l) + (size_t)r * T_SMP;
  float* ob = out + (size_t)r * (2 * T_SMP) + p * T_SMP;
  float pend[15];
  #pragma unroll
  for (int d = 0; d < 15; ++d) pend[d] = 0.0f;
  double e1 = 0.0, e2 = 0.0;
  for (int t = 0; t < T_SMP; ++t) {
    double xv = (double)base[t];
    e1 = IIR_A * e1 + xv;
    e2 = IIR_A * e2 + e1;
    float uf = (float)(IIR_CK * (e2 - e1));
    float um = uf + pend[0];
    float s  = (um >= 10.0f) ? 1.0f : 0.0f;
    #pragma unroll
    for (int d = 0; d < 14; ++d) pend[d] = fmaf(s, REFN_C[d], pend[d + 1]);
    pend[14] = s * REFN_C[14];
    ob[t] = s;
  }
}

// ---------------------------------------------------------------------------
extern "C" void kernel_launch(void* const* d_in, const int* in_sizes, int n_in,
                              void* d_out, int out_size, void* d_ws, size_t ws_size,
                              hipStream_t stream) {
  const float* x      = (const float*)d_in[0];
  const float* w_fc1  = (const float*)d_in[1];
  const float* w_fc2  = (const float*)d_in[2];
  const float* w_loc1 = (const float*)d_in[3];
  const float* w_loc2 = (const float*)d_in[4];
  float* out = (float*)d_out;
  char* ws = (char*)d_ws;

  // workspace layout
  uint32_t* lists_m = (uint32_t*)(ws + 0);          //  3,194,880
  uint32_t* lists_l = (uint32_t*)(ws + 3194880);    //  3,194,880
  uint32_t* cnt_m   = (uint32_t*)(ws + 6389760);    //     79,872
  uint32_t* cnt_l   = (uint32_t*)(ws + 6469632);    //     79,872
  uint64_t* s1m_m   = (uint64_t*)(ws + 6549504);    //  2,555,904
  uint64_t* s1m_l   = (uint64_t*)(ws + 9105408);    //  2,555,904
  float*    u2_m    = (float*)   (ws + 11661312);   //  1,597,440
  float*    u2_l    = (float*)   (ws + 13258752);   //  1,597,440

  hipLaunchKernelGGL(k_build_lists, dim3(128), dim3(256),
                     C_IN * T_SMP * sizeof(float), stream,
                     x, lists_m, cnt_m, lists_l, cnt_l);
  hipLaunchKernelGGL(k_layer1, dim3(16, 32, 2), dim3(256),
                     157 * 64 * sizeof(float), stream,
                     w_fc1, w_loc1, lists_m, cnt_m, lists_l, cnt_l, s1m_m, s1m_l);
  hipLaunchKernelGGL(k_layer2, dim3(512, 2), dim3(512),
                     H_HID * O_OUT * sizeof(float), stream,
                     w_fc2, w_loc2, s1m_m, s1m_l, u2_m, u2_l);
  hipLaunchKernelGGL(k_psp_spike_out, dim3(20), dim3(256), 0, stream,
                     u2_m, u2_l, out);
}